// Round 7
// baseline (136.610 us; speedup 1.0000x reference)
//
#include <hip/hip_runtime.h>
#include <math.h>

#define EPSV 1e-8f

// ---------------- math ------------------------------------------------------
// Per node n with unit incident dirs d_i = (cos phi_i, sin phi_i):
//   0.5*(S2-S4) = (u^2 - C^2 - S^2)/16,  C = sum cos(4 phi_i), S = sum sin(4 phi_i)
//   u = deg - z (z = zero-length self-edge dirs, which contribute nothing)
// Record (u32): [31] z | [30:23] local node id (8b) | [22:11] c4q | [10:0] s4q
//   unit dir:  c4q = round((c4+1)*1024) in [0,2048]; s4q = round((s4+1)*512) in [0,1024]
//   zero dir:  z=1, c4q=1024, s4q=512 (same +1 bias, encodes c4=s4=0)
// Accumulator (u64): {z:4 @60 | deg:8 @52 | c4sum:26 @26 | s4sum:26 @0}
//   decode: C = c4sum/1024 - deg ; S = s4sum/512 - deg ; u = deg - z
static constexpr double QC = 1.0 / 1024.0;
static constexpr double QS = 1.0 / 512.0;

static constexpr int BLOG = 8;               // 256 nodes per bucket
static constexpr int NPB = 1 << BLOG;
static constexpr int NBIN = 1024;            // bin blocks (each sorts its own chunk)
static constexpr int SRTN = 4096;            // LDS sort capacity (records)
static constexpr int NREP = 8;               // LDS accumulator replication (bucket)
static constexpr int NODE_BLOCKS = 256;      // fallback path

__device__ __forceinline__ unsigned int make_record(float dx, float dy) {
    float n2 = dx * dx + dy * dy;
    if (n2 > EPSV * EPSV) {
        float inv = 1.0f / n2;
        // double angle twice without sqrt: c2=cos2phi, s2=sin2phi from (dx,dy)
        float c2 = (dx * dx - dy * dy) * inv;
        float s2 = (2.0f * dx * dy) * inv;
        float c4 = c2 * c2 - s2 * s2;
        float s4 = 2.0f * c2 * s2;
        c4 = fminf(fmaxf(c4, -1.0f), 1.0f);
        s4 = fminf(fmaxf(s4, -1.0f), 1.0f);
        unsigned int c4q = (unsigned int)__float2int_rn((c4 + 1.0f) * 1024.0f);
        unsigned int s4q = (unsigned int)__float2int_rn((s4 + 1.0f) * 512.0f);
        return (c4q << 11) | s4q;
    }
    return (1u << 31) | (1024u << 11) | 512u;   // zero-length dir (self-edge)
}

__device__ __forceinline__ unsigned long long rec_to_val(unsigned int r) {
    return (((unsigned long long)(r >> 31)) << 60) | (1ull << 52)
         | (((unsigned long long)((r >> 11) & 0xFFFu)) << 26)
         | (unsigned long long)(r & 0x7FFu);
}

__device__ __forceinline__ void decode_accum(unsigned long long a, double& pls, double& npr) {
    double s4sum = (double)(a & 0x3FFFFFFull);
    double c4sum = (double)((a >> 26) & 0x3FFFFFFull);
    double deg = (double)((a >> 52) & 0xFFull);
    double z = (double)(a >> 60);
    double u = deg - z;
    double C = c4sum * QC - deg;
    double S = s4sum * QS - deg;
    pls += (u * u - C * C - S * S) * 0.0625;
    npr += 0.5 * deg * (deg - 1.0);
}

// ---------------- phase 1: per-block counting sort of records ---------------
__global__ __launch_bounds__(256) void bin_kernel(
    const float2* __restrict__ pos,
    const int* __restrict__ ei,        // (2,E): src row then dst row
    int E, int NB, int chunk, int rstride,
    unsigned short* __restrict__ ofs,  // [NB+1][NBIN] bucket-major offsets
    unsigned int* __restrict__ buf)    // [NBIN][rstride] sorted records
{
    __shared__ unsigned int srt[SRTN];
    __shared__ unsigned int hist[512];
    __shared__ unsigned int scan[512];
    int blk = blockIdx.x;
    int t = threadIdx.x;
    int e0 = blk * chunk;
    int e1 = min(E, e0 + chunk);
    const int* src = ei;
    const int* dst = ei + E;

    hist[t] = 0; hist[t + 256] = 0;
    __syncthreads();
    for (int e = e0 + t; e < e1; e += 256) {
        atomicAdd(&hist[src[e] >> BLOG], 1u);
        atomicAdd(&hist[dst[e] >> BLOG], 1u);
    }
    __syncthreads();
    // inclusive Hillis-Steele scan over 512 slots
    scan[t] = hist[t]; scan[t + 256] = hist[t + 256];
    __syncthreads();
    for (int d = 1; d < 512; d <<= 1) {
        unsigned a0 = scan[t] + ((t >= d) ? scan[t - d] : 0u);
        int t2 = t + 256;
        unsigned a1 = scan[t2] + ((t2 >= d) ? scan[t2 - d] : 0u);
        __syncthreads();
        scan[t] = a0; scan[t2] = a1;
        __syncthreads();
    }
    // exclusive offsets; row NB (= slot NB) automatically equals total count
    unsigned ex0 = scan[t] - hist[t];
    unsigned ex1 = scan[t + 256] - hist[t + 256];
    if (t <= NB) ofs[(size_t)t * NBIN + blk] = (unsigned short)ex0;
    if (t + 256 <= NB) ofs[(size_t)(t + 256) * NBIN + blk] = (unsigned short)ex1;
    __syncthreads();
    hist[t] = ex0; hist[t + 256] = ex1;
    __syncthreads();
    // place records into LDS sorted array (counting sort is exact; no guards)
    for (int e = e0 + t; e < e1; e += 256) {
        int s = src[e], d = dst[e];
        float2 ps = pos[s], pd = pos[d];
        unsigned int rec = make_record(pd.x - ps.x, pd.y - ps.y);
        unsigned is = atomicAdd(&hist[s >> BLOG], 1u);
        srt[is] = rec | ((unsigned)(s & (NPB - 1)) << 23);
        unsigned it = atomicAdd(&hist[d >> BLOG], 1u);
        srt[it] = rec | ((unsigned)(d & (NPB - 1)) << 23);
    }
    __syncthreads();
    // coalesced vectorized copy-out of the block's private sorted region
    int nrec = 2 * max(0, e1 - e0);
    unsigned int* db = buf + (size_t)blk * (size_t)rstride;
    int nv = nrec >> 2;
    const uint4* s4 = (const uint4*)srt;
    uint4* d4 = (uint4*)db;
    for (int i = t; i < nv; i += 256) d4[i] = s4[i];
    for (int i = (nv << 2) + t; i < nrec; i += 256) db[i] = srt[i];
}

// ---------------- phase 2: per-bucket LDS reduction (1024 threads) ----------
__global__ __launch_bounds__(1024) void bucket_kernel(
    const unsigned int* __restrict__ buf,
    const unsigned short* __restrict__ ofs,
    int rstride,
    double* __restrict__ partials)     // 2 doubles per bucket
{
    __shared__ unsigned long long acc[NREP][NPB];
    __shared__ unsigned short o0s[NBIN], o1s[NBIN];
    __shared__ double sha[16], shb[16];
    int b = blockIdx.x;
    int t = threadIdx.x;
    int wid = t >> 6;
    for (int i = t; i < NREP * NPB; i += 1024)
        ((unsigned long long*)acc)[i] = 0ull;
    for (int i = t; i < NBIN; i += 1024) {
        o0s[i] = ofs[(size_t)b * NBIN + i];        // coalesced row reads
        o1s[i] = ofs[(size_t)(b + 1) * NBIN + i];
    }
    __syncthreads();

    int rep = wid & (NREP - 1);
    for (int run = t; run < NBIN; run += 1024) {
        const unsigned int* p = buf + (size_t)run * (size_t)rstride;
        int i0 = o0s[run], i1 = o1s[run];
        for (int i = i0; i < i1; ++i) {
            unsigned r = p[i];
            atomicAdd(&acc[rep][(r >> 23) & (NPB - 1)], rec_to_val(r));
        }
    }
    __syncthreads();

    double pls = 0.0, npr = 0.0;
    for (int i = t; i < NPB; i += 1024) {
        unsigned long long a = 0;
        for (int rr = 0; rr < NREP; ++rr) a += acc[rr][i];
        decode_accum(a, pls, npr);
    }
    for (int off = 32; off > 0; off >>= 1) {
        pls += __shfl_down(pls, off, 64);
        npr += __shfl_down(npr, off, 64);
    }
    if ((t & 63) == 0) { sha[wid] = pls; shb[wid] = npr; }
    __syncthreads();
    if (t == 0) {
        double a = 0.0, bb = 0.0;
        for (int i = 0; i < 16; ++i) { a += sha[i]; bb += shb[i]; }
        partials[2 * b + 0] = a;
        partials[2 * b + 1] = bb;
    }
}

// ---------------- final: sum partials, divide -------------------------------
__global__ __launch_bounds__(256) void final_kernel(
    const double* __restrict__ partials,
    float* __restrict__ out,
    int nb)
{
    double pls = 0.0, npr = 0.0;
    for (int i = threadIdx.x; i < nb; i += blockDim.x) {
        pls += partials[2 * i + 0];
        npr += partials[2 * i + 1];
    }
    __shared__ double sha[4], shb[4];
    for (int off = 32; off > 0; off >>= 1) {
        pls += __shfl_down(pls, off, 64);
        npr += __shfl_down(npr, off, 64);
    }
    int lane = threadIdx.x & 63;
    int wid = threadIdx.x >> 6;
    if (lane == 0) { sha[wid] = pls; shb[wid] = npr; }
    __syncthreads();
    if (threadIdx.x == 0) {
        double a = sha[0] + sha[1] + sha[2] + sha[3];
        double b = shb[0] + shb[1] + shb[2] + shb[3];
        out[0] = (float)(a / fmax(b, 1.0));
    }
}

// ---------------- fallback path (round-2 proven): device atomics ------------
__global__ __launch_bounds__(256) void edge_kernel_fb(
    const float2* __restrict__ pos,
    const int* __restrict__ ei,
    unsigned long long* __restrict__ acc,
    int E)
{
    int tid = blockIdx.x * blockDim.x + threadIdx.x;
    int nthreads = gridDim.x * blockDim.x;
    const int* src = ei;
    const int* dst = ei + E;
    for (int e = tid; e < E; e += nthreads) {
        int s = src[e], t = dst[e];
        float2 ps = pos[s], pt = pos[t];
        unsigned long long val = rec_to_val(make_record(pt.x - ps.x, pt.y - ps.y));
        atomicAdd(&acc[s], val);
        atomicAdd(&acc[t], val);
    }
}

__global__ __launch_bounds__(256) void node_kernel_fb(
    const unsigned long long* __restrict__ acc,
    double* __restrict__ partials,
    int N)
{
    int tid = blockIdx.x * blockDim.x + threadIdx.x;
    int nthreads = gridDim.x * blockDim.x;
    double pls = 0.0, npr = 0.0;
    for (int n = tid; n < N; n += nthreads)
        decode_accum(acc[n], pls, npr);
    __shared__ double sha[4], shb[4];
    for (int off = 32; off > 0; off >>= 1) {
        pls += __shfl_down(pls, off, 64);
        npr += __shfl_down(npr, off, 64);
    }
    int lane = threadIdx.x & 63;
    int wid = threadIdx.x >> 6;
    if (lane == 0) { sha[wid] = pls; shb[wid] = npr; }
    __syncthreads();
    if (threadIdx.x == 0) {
        partials[2 * blockIdx.x + 0] = sha[0] + sha[1] + sha[2] + sha[3];
        partials[2 * blockIdx.x + 1] = shb[0] + shb[1] + shb[2] + shb[3];
    }
}

extern "C" void kernel_launch(void* const* d_in, const int* in_sizes, int n_in,
                              void* d_out, int out_size, void* d_ws, size_t ws_size,
                              hipStream_t stream) {
    const float* pos = (const float*)d_in[0];   // (1,N,2) interleaved x,y
    const int* ei = (const int*)d_in[2];        // (2,E)
    int N = in_sizes[0] / 2;
    int E = in_sizes[2] / 2;
    float* out = (float*)d_out;

    int NB = (N + NPB - 1) >> BLOG;
    int chunk = (E + NBIN - 1) / NBIN;
    int nrec_max = 2 * chunk;
    int rstride = (nrec_max + 15) & ~15;        // 64 B-aligned regions

    // ws layout: [partials NB*16][buf NBIN*rstride*4][ofs (NB+1)*NBIN*2]
    size_t off_buf = (size_t)NB * 16;
    size_t off_ofs = off_buf + (size_t)NBIN * (size_t)rstride * 4;
    size_t need = off_ofs + (size_t)(NB + 1) * (size_t)NBIN * 2;

    if (ws_size >= need && nrec_max <= SRTN && NB + 1 <= 512) {
        double* partials = (double*)d_ws;
        unsigned int* buf = (unsigned int*)((char*)d_ws + off_buf);
        unsigned short* ofs = (unsigned short*)((char*)d_ws + off_ofs);

        bin_kernel<<<NBIN, 256, 0, stream>>>(
            (const float2*)pos, ei, E, NB, chunk, rstride, ofs, buf);
        bucket_kernel<<<NB, 1024, 0, stream>>>(buf, ofs, rstride, partials);
        final_kernel<<<1, 256, 0, stream>>>(partials, out, NB);
    } else {
        // fallback: device-atomic accumulation (round-2 proven path)
        unsigned long long* acc = (unsigned long long*)d_ws;
        double* partials = (double*)((char*)d_ws + (size_t)N * 8);
        hipMemsetAsync(d_ws, 0, (size_t)N * 8 + (size_t)NODE_BLOCKS * 16, stream);
        int eb = min((E + 255) / 256, 2048);
        edge_kernel_fb<<<eb, 256, 0, stream>>>((const float2*)pos, ei, acc, E);
        node_kernel_fb<<<NODE_BLOCKS, 256, 0, stream>>>(acc, partials, N);
        final_kernel<<<1, 256, 0, stream>>>(partials, out, NODE_BLOCKS);
    }
}

// Round 8
// 117.212 us; speedup vs baseline: 1.1655x; 1.1655x over previous
//
#include <hip/hip_runtime.h>
#include <math.h>

#define EPSV 1e-8f

// ---------------- math ------------------------------------------------------
// Per node n with unit incident dirs d_i = (cos phi_i, sin phi_i):
//   0.5*(S2-S4) = (u^2 - C^2 - S^2)/16,  C = sum cos(4 phi_i), S = sum sin(4 phi_i)
//   u = deg - z (z = zero-length self-edge dirs, which contribute nothing)
// Record (u32): [31] z | [30:23] local node id (8b) | [22:11] c4q | [10:0] s4q
//   unit dir:  c4q = round((c4+1)*1024) in [0,2048]; s4q = round((s4+1)*512) in [0,1024]
//   zero dir:  z=1, c4q=1024, s4q=512 (same +1 bias, encodes c4=s4=0)
// Accumulator (u64): {z:4 @60 | deg:8 @52 | c4sum:26 @26 | s4sum:26 @0}
//   decode: C = c4sum/1024 - deg ; S = s4sum/512 - deg ; u = deg - z
static constexpr double QC = 1.0 / 1024.0;
static constexpr double QS = 1.0 / 512.0;

static constexpr int BLOG = 8;               // 256 nodes per bucket
static constexpr int NPB = 1 << BLOG;
static constexpr int NBIN = 512;             // bin blocks (each sorts its own chunk)
static constexpr int SRTN = 8192;            // LDS sort capacity (records)
static constexpr int NREP = 8;               // LDS accumulator replication (bucket)
static constexpr int NODE_BLOCKS = 256;      // fallback path

__device__ __forceinline__ unsigned int make_record(float dx, float dy) {
    float n2 = dx * dx + dy * dy;
    if (n2 > EPSV * EPSV) {
        float inv = 1.0f / n2;
        // double angle twice without sqrt: c2=cos2phi, s2=sin2phi from (dx,dy)
        float c2 = (dx * dx - dy * dy) * inv;
        float s2 = (2.0f * dx * dy) * inv;
        float c4 = c2 * c2 - s2 * s2;
        float s4 = 2.0f * c2 * s2;
        c4 = fminf(fmaxf(c4, -1.0f), 1.0f);
        s4 = fminf(fmaxf(s4, -1.0f), 1.0f);
        unsigned int c4q = (unsigned int)__float2int_rn((c4 + 1.0f) * 1024.0f);
        unsigned int s4q = (unsigned int)__float2int_rn((s4 + 1.0f) * 512.0f);
        return (c4q << 11) | s4q;
    }
    return (1u << 31) | (1024u << 11) | 512u;   // zero-length dir (self-edge)
}

__device__ __forceinline__ unsigned long long rec_to_val(unsigned int r) {
    return (((unsigned long long)(r >> 31)) << 60) | (1ull << 52)
         | (((unsigned long long)((r >> 11) & 0xFFFu)) << 26)
         | (unsigned long long)(r & 0x7FFu);
}

__device__ __forceinline__ void decode_accum(unsigned long long a, double& pls, double& npr) {
    double s4sum = (double)(a & 0x3FFFFFFull);
    double c4sum = (double)((a >> 26) & 0x3FFFFFFull);
    double deg = (double)((a >> 52) & 0xFFull);
    double z = (double)(a >> 60);
    double u = deg - z;
    double C = c4sum * QC - deg;
    double S = s4sum * QS - deg;
    pls += (u * u - C * C - S * S) * 0.0625;
    npr += 0.5 * deg * (deg - 1.0);
}

// ---------------- phase 1: per-block counting sort of records ---------------
__global__ __launch_bounds__(256) void bin_kernel(
    const float2* __restrict__ pos,
    const int* __restrict__ ei,        // (2,E): src row then dst row
    int E, int NB, int chunk, int rstride,
    unsigned short* __restrict__ ofs,  // [NB+1][NBIN] bucket-major offsets
    unsigned int* __restrict__ buf)    // [NBIN][rstride] sorted records
{
    __shared__ unsigned int srt[SRTN];
    __shared__ unsigned int hist[512];
    __shared__ unsigned int scan[512];
    int blk = blockIdx.x;
    int t = threadIdx.x;
    int e0 = blk * chunk;
    int e1 = min(E, e0 + chunk);
    const int* src = ei;
    const int* dst = ei + E;

    hist[t] = 0; hist[t + 256] = 0;
    __syncthreads();
    for (int e = e0 + t; e < e1; e += 256) {
        atomicAdd(&hist[src[e] >> BLOG], 1u);
        atomicAdd(&hist[dst[e] >> BLOG], 1u);
    }
    __syncthreads();
    // inclusive Hillis-Steele scan over 512 slots
    scan[t] = hist[t]; scan[t + 256] = hist[t + 256];
    __syncthreads();
    for (int d = 1; d < 512; d <<= 1) {
        unsigned a0 = scan[t] + ((t >= d) ? scan[t - d] : 0u);
        int t2 = t + 256;
        unsigned a1 = scan[t2] + ((t2 >= d) ? scan[t2 - d] : 0u);
        __syncthreads();
        scan[t] = a0; scan[t2] = a1;
        __syncthreads();
    }
    // exclusive offsets -> transposed (bucket-major) table; slot NB = total
    unsigned ex0 = scan[t] - hist[t];
    unsigned ex1 = scan[t + 256] - hist[t + 256];
    if (t <= NB) ofs[(size_t)t * NBIN + blk] = (unsigned short)ex0;
    if (t + 256 <= NB) ofs[(size_t)(t + 256) * NBIN + blk] = (unsigned short)ex1;
    __syncthreads();
    hist[t] = ex0; hist[t + 256] = ex1;
    __syncthreads();
    // place records into LDS sorted array (counting sort is exact; no guards)
    for (int e = e0 + t; e < e1; e += 256) {
        int s = src[e], d = dst[e];
        float2 ps = pos[s], pd = pos[d];
        unsigned int rec = make_record(pd.x - ps.x, pd.y - ps.y);
        unsigned is = atomicAdd(&hist[s >> BLOG], 1u);
        srt[is] = rec | ((unsigned)(s & (NPB - 1)) << 23);
        unsigned it = atomicAdd(&hist[d >> BLOG], 1u);
        srt[it] = rec | ((unsigned)(d & (NPB - 1)) << 23);
    }
    __syncthreads();
    // coalesced vectorized copy-out of the block's private sorted region
    int nrec = 2 * max(0, e1 - e0);
    unsigned int* db = buf + (size_t)blk * (size_t)rstride;
    int nv = nrec >> 2;
    const uint4* s4 = (const uint4*)srt;
    uint4* d4 = (uint4*)db;
    for (int i = t; i < nv; i += 256) d4[i] = s4[i];
    for (int i = (nv << 2) + t; i < nrec; i += 256) db[i] = srt[i];
}

// ---------------- phase 2: per-bucket flattened LDS reduction ---------------
// Records for bucket b live in NBIN short runs. We flatten them into one index
// space via an LDS prefix scan of run lengths; thread t consumes global record
// t, t+1024, ... and binary-searches its run. Consecutive lanes -> consecutive
// addresses within a run (coalesced, lines consumed immediately -> no L1 thrash).
__global__ __launch_bounds__(1024) void bucket_kernel(
    const unsigned int* __restrict__ buf,
    const unsigned short* __restrict__ ofs,
    int rstride,
    double* __restrict__ partials)     // 2 doubles per bucket
{
    __shared__ unsigned long long acc[NREP][NPB];
    __shared__ unsigned short o0s[NBIN];
    __shared__ unsigned int sc[NBIN + 1];   // exclusive/inclusive scan of run lengths
    __shared__ double sha[16], shb[16];
    int b = blockIdx.x;
    int t = threadIdx.x;
    int wid = t >> 6;
    for (int i = t; i < NREP * NPB; i += 1024)
        ((unsigned long long*)acc)[i] = 0ull;
    if (t < NBIN) {
        unsigned o0 = ofs[(size_t)b * NBIN + t];       // coalesced row reads
        unsigned o1 = ofs[(size_t)(b + 1) * NBIN + t];
        o0s[t] = (unsigned short)o0;
        sc[t + 1] = o1 - o0;
    }
    if (t == 0) sc[0] = 0;
    __syncthreads();
    // inclusive scan over sc[1..NBIN]
    for (int d = 1; d < NBIN; d <<= 1) {
        unsigned v = 0;
        if (t < NBIN) v = sc[t + 1] + ((t + 1 > d) ? sc[t + 1 - d] : 0u);
        __syncthreads();
        if (t < NBIN) sc[t + 1] = v;
        __syncthreads();
    }
    int cnt = sc[NBIN];

    int rep = wid & (NREP - 1);
    for (int idx = t; idx < cnt; idx += 1024) {
        // find run: sc[run] <= idx < sc[run+1]
        int lo = 0, hi = NBIN;
        while (hi - lo > 1) {
            int mid = (lo + hi) >> 1;
            if ((unsigned)idx >= sc[mid]) lo = mid; else hi = mid;
        }
        unsigned r = buf[(size_t)lo * (size_t)rstride + o0s[lo] + (unsigned)idx - sc[lo]];
        atomicAdd(&acc[rep][(r >> 23) & (NPB - 1)], rec_to_val(r));
    }
    __syncthreads();

    double pls = 0.0, npr = 0.0;
    for (int i = t; i < NPB; i += 1024) {
        unsigned long long a = 0;
        for (int rr = 0; rr < NREP; ++rr) a += acc[rr][i];
        decode_accum(a, pls, npr);
    }
    for (int off = 32; off > 0; off >>= 1) {
        pls += __shfl_down(pls, off, 64);
        npr += __shfl_down(npr, off, 64);
    }
    if ((t & 63) == 0) { sha[wid] = pls; shb[wid] = npr; }
    __syncthreads();
    if (t == 0) {
        double a = 0.0, bb = 0.0;
        for (int i = 0; i < 16; ++i) { a += sha[i]; bb += shb[i]; }
        partials[2 * b + 0] = a;
        partials[2 * b + 1] = bb;
    }
}

// ---------------- final: sum partials, divide -------------------------------
__global__ __launch_bounds__(256) void final_kernel(
    const double* __restrict__ partials,
    float* __restrict__ out,
    int nb)
{
    double pls = 0.0, npr = 0.0;
    for (int i = threadIdx.x; i < nb; i += blockDim.x) {
        pls += partials[2 * i + 0];
        npr += partials[2 * i + 1];
    }
    __shared__ double sha[4], shb[4];
    for (int off = 32; off > 0; off >>= 1) {
        pls += __shfl_down(pls, off, 64);
        npr += __shfl_down(npr, off, 64);
    }
    int lane = threadIdx.x & 63;
    int wid = threadIdx.x >> 6;
    if (lane == 0) { sha[wid] = pls; shb[wid] = npr; }
    __syncthreads();
    if (threadIdx.x == 0) {
        double a = sha[0] + sha[1] + sha[2] + sha[3];
        double b = shb[0] + shb[1] + shb[2] + shb[3];
        out[0] = (float)(a / fmax(b, 1.0));
    }
}

// ---------------- fallback path (round-2 proven): device atomics ------------
__global__ __launch_bounds__(256) void edge_kernel_fb(
    const float2* __restrict__ pos,
    const int* __restrict__ ei,
    unsigned long long* __restrict__ acc,
    int E)
{
    int tid = blockIdx.x * blockDim.x + threadIdx.x;
    int nthreads = gridDim.x * blockDim.x;
    const int* src = ei;
    const int* dst = ei + E;
    for (int e = tid; e < E; e += nthreads) {
        int s = src[e], t = dst[e];
        float2 ps = pos[s], pt = pos[t];
        unsigned long long val = rec_to_val(make_record(pt.x - ps.x, pt.y - ps.y));
        atomicAdd(&acc[s], val);
        atomicAdd(&acc[t], val);
    }
}

__global__ __launch_bounds__(256) void node_kernel_fb(
    const unsigned long long* __restrict__ acc,
    double* __restrict__ partials,
    int N)
{
    int tid = blockIdx.x * blockDim.x + threadIdx.x;
    int nthreads = gridDim.x * blockDim.x;
    double pls = 0.0, npr = 0.0;
    for (int n = tid; n < N; n += nthreads)
        decode_accum(acc[n], pls, npr);
    __shared__ double sha[4], shb[4];
    for (int off = 32; off > 0; off >>= 1) {
        pls += __shfl_down(pls, off, 64);
        npr += __shfl_down(npr, off, 64);
    }
    int lane = threadIdx.x & 63;
    int wid = threadIdx.x >> 6;
    if (lane == 0) { sha[wid] = pls; shb[wid] = npr; }
    __syncthreads();
    if (threadIdx.x == 0) {
        partials[2 * blockIdx.x + 0] = sha[0] + sha[1] + sha[2] + sha[3];
        partials[2 * blockIdx.x + 1] = shb[0] + shb[1] + shb[2] + shb[3];
    }
}

extern "C" void kernel_launch(void* const* d_in, const int* in_sizes, int n_in,
                              void* d_out, int out_size, void* d_ws, size_t ws_size,
                              hipStream_t stream) {
    const float* pos = (const float*)d_in[0];   // (1,N,2) interleaved x,y
    const int* ei = (const int*)d_in[2];        // (2,E)
    int N = in_sizes[0] / 2;
    int E = in_sizes[2] / 2;
    float* out = (float*)d_out;

    int NB = (N + NPB - 1) >> BLOG;
    int chunk = (E + NBIN - 1) / NBIN;
    int nrec_max = 2 * chunk;
    int rstride = (nrec_max + 15) & ~15;        // 64 B-aligned regions

    // ws layout: [partials NB*16][buf NBIN*rstride*4][ofs (NB+1)*NBIN*2]
    size_t off_buf = (size_t)NB * 16;
    size_t off_ofs = off_buf + (size_t)NBIN * (size_t)rstride * 4;
    size_t need = off_ofs + (size_t)(NB + 1) * (size_t)NBIN * 2;

    if (ws_size >= need && nrec_max <= SRTN && NB + 1 <= 512 && nrec_max < 65536) {
        double* partials = (double*)d_ws;
        unsigned int* buf = (unsigned int*)((char*)d_ws + off_buf);
        unsigned short* ofs = (unsigned short*)((char*)d_ws + off_ofs);

        bin_kernel<<<NBIN, 256, 0, stream>>>(
            (const float2*)pos, ei, E, NB, chunk, rstride, ofs, buf);
        bucket_kernel<<<NB, 1024, 0, stream>>>(buf, ofs, rstride, partials);
        final_kernel<<<1, 256, 0, stream>>>(partials, out, NB);
    } else {
        // fallback: device-atomic accumulation (round-2 proven path)
        unsigned long long* acc = (unsigned long long*)d_ws;
        double* partials = (double*)((char*)d_ws + (size_t)N * 8);
        hipMemsetAsync(d_ws, 0, (size_t)N * 8 + (size_t)NODE_BLOCKS * 16, stream);
        int eb = min((E + 255) / 256, 2048);
        edge_kernel_fb<<<eb, 256, 0, stream>>>((const float2*)pos, ei, acc, E);
        node_kernel_fb<<<NODE_BLOCKS, 256, 0, stream>>>(acc, partials, N);
        final_kernel<<<1, 256, 0, stream>>>(partials, out, NODE_BLOCKS);
    }
}